// Round 5
// baseline (246.767 us; speedup 1.0000x reference)
//
#include <hip/hip_runtime.h>
#include <hip/hip_fp16.h>

#define BATCH   512
#define IN_DIM  16384
#define KNN     32

typedef __attribute__((ext_vector_type(4))) _Float16 half4v;

// ---------------------------------------------------------------------------
// Real XCD id from hardware (verified on MI355X: returns 0..7).
// ---------------------------------------------------------------------------
__device__ __forceinline__ int xcd_id() {
    int x;
    asm volatile("s_getreg_b32 %0, hwreg(HW_REG_XCC_ID)" : "=s"(x));
    return x & 7;
}

// ---------------------------------------------------------------------------
// Transpose x (BATCH, IN_DIM) fp32 -> xt (IN_DIM, BATCH) fp16.
// ---------------------------------------------------------------------------
__global__ __launch_bounds__(256) void transpose_h(const float* __restrict__ in,
                                                   _Float16* __restrict__ out) {
    __shared__ float tile[32][33];
    const int bx = blockIdx.x * 32;          // IN_DIM base
    const int by = blockIdx.y * 32;          // BATCH base
    const int tx = threadIdx.x & 31;
    const int ty = threadIdx.x >> 5;         // 0..7
#pragma unroll
    for (int j = 0; j < 32; j += 8)
        tile[ty + j][tx] = in[(size_t)(by + ty + j) * IN_DIM + bx + tx];
    __syncthreads();
    const int r = threadIdx.x >> 3;          // 0..31  (local d)
    const int c = (threadIdx.x & 7) * 4;     // local batch base
    half4v h;
    h[0] = (_Float16)tile[c + 0][r];
    h[1] = (_Float16)tile[c + 1][r];
    h[2] = (_Float16)tile[c + 2][r];
    h[3] = (_Float16)tile[c + 3][r];
    *(half4v*)(out + (size_t)(bx + r) * BATCH + by + c) = h;
}

// ---------------------------------------------------------------------------
// LCN layer with TRUE XCD-pinned batch chunks via per-XCD work queues.
// Chunk c's input slab (prev_dim x 64 x 2B <= 2 MB) stays in XCD c's L2.
// Block grabs items of 8 features for its OWN xcd's chunk (atomic counter);
// after its queue drains it work-steals the other 7 queues (correctness does
// not depend on XCC_ID values -- any block can process any chunk).
// Inner loop == R2's proven structure: 32 scalar-uniform knn/w loads (s_load,
// forced by readfirstlane on t and wv), 32 fp16 gathers of 128B/wave.
// ---------------------------------------------------------------------------
template<int DOUT>
__global__ __launch_bounds__(256) void lcn_xcd(const _Float16* __restrict__ xt,
                                               const float* __restrict__ w,
                                               const float* __restrict__ bias,
                                               const int* __restrict__ knn,
                                               _Float16* __restrict__ yt,
                                               int* __restrict__ counters) {
    __shared__ int s_t;
    const int lane   = threadIdx.x & 63;
    const int wv     = __builtin_amdgcn_readfirstlane(threadIdx.x >> 6); // scalar!
    const int my_xcd = xcd_id();

    for (int q = 0; q < 8; ++q) {
        const int chunk = (my_xcd + q) & 7;
        int* ctr = counters + chunk * 32;            // 128B-spaced counters
        const int b = chunk * 64 + lane;
        const _Float16* xb = xt + b;
        for (;;) {
            if (threadIdx.x == 0) {
                // relaxed pre-check: stale "not done" -> atomic (safe);
                // counters only grow, so "done" is never stale.
                int cur = __hip_atomic_load(ctr, __ATOMIC_RELAXED,
                                            __HIP_MEMORY_SCOPE_AGENT);
                s_t = (cur * 8 < DOUT) ? atomicAdd(ctr, 1) : (DOUT / 8);
            }
            __syncthreads();
            const int t = __builtin_amdgcn_readfirstlane(s_t);   // scalar!
            __syncthreads();
            if (t * 8 >= DOUT) break;                // block-uniform
#pragma unroll
            for (int j = 0; j < 2; ++j) {
                const int d = t * 8 + wv * 2 + j;
                const int*   kp = knn + (size_t)d * KNN;
                const float* wp = w   + (size_t)d * KNN;
                float acc = 0.f;
#pragma unroll
                for (int k = 0; k < KNN; ++k) {
                    const int   idx = kp[k];                      // s_load
                    const float wvv = wp[k];                      // s_load
                    acc += wvv * (float)xb[(size_t)idx * BATCH];  // 128B/wave
                }
                yt[(size_t)d * BATCH + b] = (_Float16)fmaxf(acc + bias[d], 0.f);
            }
        }
    }
}

// ---------------------------------------------------------------------------
// FC stage 1: partial sums over d-chunks of 256.
// ---------------------------------------------------------------------------
__global__ __launch_bounds__(256) void fc_partial(const _Float16* __restrict__ y2t,
                                                  const float* __restrict__ fcw,
                                                  float* __restrict__ part) {
    const int o  = blockIdx.x & 15;
    const int bh = (blockIdx.x >> 4) & 1;
    const int ch = blockIdx.x >> 5;          // 0..7
    const int b  = bh * 256 + threadIdx.x;
    const int d0 = ch * 256;
    float a0 = 0.f, a1 = 0.f, a2 = 0.f, a3 = 0.f;
#pragma unroll 4
    for (int d = d0; d < d0 + 256; d += 4) {
        a0 += (float)y2t[(size_t)(d + 0) * BATCH + b] * fcw[(d + 0) * 16 + o];
        a1 += (float)y2t[(size_t)(d + 1) * BATCH + b] * fcw[(d + 1) * 16 + o];
        a2 += (float)y2t[(size_t)(d + 2) * BATCH + b] * fcw[(d + 2) * 16 + o];
        a3 += (float)y2t[(size_t)(d + 3) * BATCH + b] * fcw[(d + 3) * 16 + o];
    }
    part[((size_t)b * 16 + o) * 8 + ch] = (a0 + a1) + (a2 + a3);
}

__global__ __launch_bounds__(256) void fc_final(const float* __restrict__ part,
                                                const float* __restrict__ fcb,
                                                float* __restrict__ out) {
    const int t = blockIdx.x * 256 + threadIdx.x;       // 0..8191
    const float4 p0 = *(const float4*)(part + (size_t)t * 8);
    const float4 p1 = *(const float4*)(part + (size_t)t * 8 + 4);
    out[t] = ((p0.x + p0.y) + (p0.z + p0.w)) + ((p1.x + p1.y) + (p1.z + p1.w))
             + fcb[t & 15];
}

extern "C" void kernel_launch(void* const* d_in, const int* in_sizes, int n_in,
                              void* d_out, int out_size, void* d_ws, size_t ws_size,
                              hipStream_t stream) {
    // setup_inputs() order: x, w0,b0,knn0, w1,b1,knn1, w2,b2,knn2, fc_w, fc_b
    const float* x    = (const float*)d_in[0];
    const float* w0   = (const float*)d_in[1];
    const float* b0   = (const float*)d_in[2];
    const int*   knn0 = (const int*)  d_in[3];
    const float* w1   = (const float*)d_in[4];
    const float* b1   = (const float*)d_in[5];
    const int*   knn1 = (const int*)  d_in[6];
    const float* w2   = (const float*)d_in[7];
    const float* b2   = (const float*)d_in[8];
    const int*   knn2 = (const int*)  d_in[9];
    const float* fcw  = (const float*)d_in[10];
    const float* fcb  = (const float*)d_in[11];
    float* out = (float*)d_out;

    // Workspace:
    //   xt   @  0 MB : 16 MB    y0t @ 16 MB : 8 MB
    //   y1t  @ 24 MB :  4 MB    y2t @ 28 MB : 2 MB
    //   part @ 30 MB : 256 KB   counters @ 30.5 MB : 3 layers * 8 * 32 ints
    char* ws = (char*)d_ws;
    _Float16* xt   = (_Float16*)(ws);
    _Float16* y0t  = (_Float16*)(ws + ((size_t)16 << 20));
    _Float16* y1t  = (_Float16*)(ws + ((size_t)24 << 20));
    _Float16* y2t  = (_Float16*)(ws + ((size_t)28 << 20));
    float*    part = (float*)   (ws + ((size_t)30 << 20));
    int*      ctrs = (int*)     (ws + ((size_t)30 << 20) + (512u << 10));

    hipMemsetAsync(ctrs, 0, 3 * 8 * 32 * sizeof(int), stream);

    transpose_h<<<dim3(IN_DIM / 32, BATCH / 32), 256, 0, stream>>>(x, xt);
    // 2048 blocks x 4 waves = 8192 waves = 32 waves/CU (machine-fill).
    lcn_xcd<8192><<<2048, 256, 0, stream>>>(xt,  w0, b0, knn0, y0t, ctrs);
    lcn_xcd<4096><<<2048, 256, 0, stream>>>(y0t, w1, b1, knn1, y1t, ctrs + 8 * 32);
    lcn_xcd<2048><<<2048, 256, 0, stream>>>(y1t, w2, b2, knn2, y2t, ctrs + 16 * 32);
    fc_partial<<<256, 256, 0, stream>>>(y2t, fcw, part);
    fc_final<<<32, 256, 0, stream>>>(part, fcb, out);
}

// Round 6
// 70.639 us; speedup vs baseline: 3.4933x; 3.4933x over previous
//
#include <hip/hip_runtime.h>
#include <hip/hip_fp16.h>

#define BATCH   512
#define IN_DIM  16384
#define KNN     32

typedef __attribute__((ext_vector_type(4))) _Float16 half4v;

// ---------------------------------------------------------------------------
// Transpose x (BATCH, IN_DIM) fp32 -> xt (IN_DIM, BATCH) fp16.
// ---------------------------------------------------------------------------
__global__ __launch_bounds__(256) void transpose_h(const float* __restrict__ in,
                                                   _Float16* __restrict__ out) {
    __shared__ float tile[32][33];
    const int bx = blockIdx.x * 32;          // IN_DIM base
    const int by = blockIdx.y * 32;          // BATCH base
    const int tx = threadIdx.x & 31;
    const int ty = threadIdx.x >> 5;         // 0..7
#pragma unroll
    for (int j = 0; j < 32; j += 8)
        tile[ty + j][tx] = in[(size_t)(by + ty + j) * IN_DIM + bx + tx];
    __syncthreads();
    const int r = threadIdx.x >> 3;          // 0..31  (local d)
    const int c = (threadIdx.x & 7) * 4;     // local batch base
    half4v h;
    h[0] = (_Float16)tile[c + 0][r];
    h[1] = (_Float16)tile[c + 1][r];
    h[2] = (_Float16)tile[c + 2][r];
    h[3] = (_Float16)tile[c + 3][r];
    *(half4v*)(out + (size_t)(bx + r) * BATCH + by + c) = h;
}

// ---------------------------------------------------------------------------
// LCN layer: R2's per-wave work (1 feature x 64-batch chunk, 32 scalar-uniform
// knn/w loads + 32 fp16 gathers of 128B/wave) packed 4 waves per block.
//   d = (bid>>3)*4 + wave   with wave forced into an SGPR via readfirstlane
//   (R5 proved this pattern keeps knn/w on the s_load path: SGPR=80),
//   b = (bid&7)*64 + lane   -- all 4 waves share one chunk (chunk-pure block,
//   free XCD-locality hint via consecutive-bid round-robin).
// vs R2: 4x fewer workgroups (dispatch), 32 waves/CU possible (single-wave
// WGs cap at ~16 WG/CU). vs R4: scalar knn/w path restored.
// ---------------------------------------------------------------------------
__global__ __launch_bounds__(256) void lcn_p4(const _Float16* __restrict__ xt,
                                              const float* __restrict__ w,
                                              const float* __restrict__ bias,
                                              const int* __restrict__ knn,
                                              _Float16* __restrict__ yt) {
    const int lane = threadIdx.x & 63;
    const int wv   = __builtin_amdgcn_readfirstlane(threadIdx.x >> 6); // SGPR
    const int d    = (blockIdx.x >> 3) * 4 + wv;                       // scalar
    const int b    = (blockIdx.x & 7) * 64 + lane;
    const int*   kp = knn + (size_t)d * KNN;
    const float* wp = w   + (size_t)d * KNN;
    const _Float16* xb = xt + b;
    float acc = 0.f;
#pragma unroll
    for (int k = 0; k < KNN; ++k) {
        const int   idx = kp[k];                         // s_load
        const float wvv = wp[k];                         // s_load
        acc += wvv * (float)xb[(size_t)idx * BATCH];     // 128B/wave
    }
    acc = fmaxf(acc + bias[d], 0.f);
    yt[(size_t)d * BATCH + b] = (_Float16)acc;
}

// ---------------------------------------------------------------------------
// FC stage 1: partial sums over d-chunks of 256.
//   part[(b*16+o)*8 + ch] = sum_{d in ch} y2t[d,b] * fcw[d,o]
// ---------------------------------------------------------------------------
__global__ __launch_bounds__(256) void fc_partial(const _Float16* __restrict__ y2t,
                                                  const float* __restrict__ fcw,
                                                  float* __restrict__ part) {
    const int o  = blockIdx.x & 15;
    const int bh = (blockIdx.x >> 4) & 1;
    const int ch = blockIdx.x >> 5;          // 0..7
    const int b  = bh * 256 + threadIdx.x;
    const int d0 = ch * 256;
    float a0 = 0.f, a1 = 0.f, a2 = 0.f, a3 = 0.f;
#pragma unroll 4
    for (int d = d0; d < d0 + 256; d += 4) {
        a0 += (float)y2t[(size_t)(d + 0) * BATCH + b] * fcw[(d + 0) * 16 + o];
        a1 += (float)y2t[(size_t)(d + 1) * BATCH + b] * fcw[(d + 1) * 16 + o];
        a2 += (float)y2t[(size_t)(d + 2) * BATCH + b] * fcw[(d + 2) * 16 + o];
        a3 += (float)y2t[(size_t)(d + 3) * BATCH + b] * fcw[(d + 3) * 16 + o];
    }
    part[((size_t)b * 16 + o) * 8 + ch] = (a0 + a1) + (a2 + a3);
}

__global__ __launch_bounds__(256) void fc_final(const float* __restrict__ part,
                                                const float* __restrict__ fcb,
                                                float* __restrict__ out) {
    const int t = blockIdx.x * 256 + threadIdx.x;       // 0..8191
    const float4 p0 = *(const float4*)(part + (size_t)t * 8);
    const float4 p1 = *(const float4*)(part + (size_t)t * 8 + 4);
    out[t] = ((p0.x + p0.y) + (p0.z + p0.w)) + ((p1.x + p1.y) + (p1.z + p1.w))
             + fcb[t & 15];
}

extern "C" void kernel_launch(void* const* d_in, const int* in_sizes, int n_in,
                              void* d_out, int out_size, void* d_ws, size_t ws_size,
                              hipStream_t stream) {
    // setup_inputs() order: x, w0,b0,knn0, w1,b1,knn1, w2,b2,knn2, fc_w, fc_b
    const float* x    = (const float*)d_in[0];
    const float* w0   = (const float*)d_in[1];
    const float* b0   = (const float*)d_in[2];
    const int*   knn0 = (const int*)  d_in[3];
    const float* w1   = (const float*)d_in[4];
    const float* b1   = (const float*)d_in[5];
    const int*   knn1 = (const int*)  d_in[6];
    const float* w2   = (const float*)d_in[7];
    const float* b2   = (const float*)d_in[8];
    const int*   knn2 = (const int*)  d_in[9];
    const float* fcw  = (const float*)d_in[10];
    const float* fcb  = (const float*)d_in[11];
    float* out = (float*)d_out;

    // Workspace (fp16 intermediates, non-overlapping, 30.25 MB total):
    //   xt   @  0 MB : 16 MB    y0t @ 16 MB : 8 MB
    //   y1t  @ 24 MB :  4 MB    y2t @ 28 MB : 2 MB    part @ 30 MB : 256 KB
    char* ws = (char*)d_ws;
    _Float16* xt   = (_Float16*)(ws);
    _Float16* y0t  = (_Float16*)(ws + ((size_t)16 << 20));
    _Float16* y1t  = (_Float16*)(ws + ((size_t)24 << 20));
    _Float16* y2t  = (_Float16*)(ws + ((size_t)28 << 20));
    float*    part = (float*)   (ws + ((size_t)30 << 20));

    transpose_h<<<dim3(IN_DIM / 32, BATCH / 32), 256, 0, stream>>>(x, xt);
    // 4 features per block (one per wave), 8 chunks:
    lcn_p4<<<(8192 / 4) * 8, 256, 0, stream>>>(xt,  w0, b0, knn0, y0t);
    lcn_p4<<<(4096 / 4) * 8, 256, 0, stream>>>(y0t, w1, b1, knn1, y1t);
    lcn_p4<<<(2048 / 4) * 8, 256, 0, stream>>>(y1t, w2, b2, knn2, y2t);
    fc_partial<<<256, 256, 0, stream>>>(y2t, fcw, part);
    fc_final<<<32, 256, 0, stream>>>(part, fcb, out);
}